// Round 1
// 217.949 us; speedup vs baseline: 1.0497x; 1.0497x over previous
//
#include <hip/hip_runtime.h>

#define THREADS 256
#define ROWS 2  // rows per block: double-buffered row pipeline

typedef float f4 __attribute__((ext_vector_type(4)));

// Radix-4 in-place unnormalized WHT on 4 values.
__device__ __forceinline__ void fwht4(float& a, float& b, float& c, float& d) {
  float s0 = a + b, d0 = a - b, s1 = c + d, d1 = c - d;
  a = s0 + s1; b = d0 + d1; c = s0 - s1; d = d0 - d1;
}

// 16-point in-place WHT over v[0..15] (H16 = H4 (x) H4, order-independent).
__device__ __forceinline__ void fwht16(float v[16]) {
#pragma unroll
  for (int j = 0; j < 4; ++j) fwht4(v[j * 4 + 0], v[j * 4 + 1], v[j * 4 + 2], v[j * 4 + 3]);
#pragma unroll
  for (int j = 0; j < 4; ++j) fwht4(v[0 + j], v[4 + j], v[8 + j], v[12 + j]);
}

// LDS swizzle: logical word i -> i + 4*(i>>6). All transpose access patterns
// are <=2-way bank-aliased (free on gfx950, m136), and any 16B-aligned run of
// 4 words within a 64-block stays contiguous (ds_*_b128 legal).
__device__ __forceinline__ int pad(int i) { return i + ((i >> 6) << 2); }

__global__ __launch_bounds__(THREADS, 8) void hadamard4096_kernel(
    const float* __restrict__ in, float* __restrict__ out, int nrows) {
  // 4096 data words + 4 pad words per 64 -> 17408 B; 8 blocks/CU = 139 KB LDS.
  __shared__ __align__(16) float lds[4096 + 256];

  const int t = threadIdx.x;
  const int kk = t >> 6;
  const int ss = (t >> 2) & 15;
  const int jj = t & 3;
  // pad-folded LDS bases (verified index math — identical to prior kernel).
  const int a1base = kk * 1024 + ss * 64 + jj + 4 * (kk * 16 + ss);
  const int a2base = kk * 1088 + 4 * ss + jj;

  const int row0 = blockIdx.x * ROWS;
  const f4* in4 = reinterpret_cast<const f4*>(in) + (size_t)row0 * 1024 + t;
  float* op = out + (size_t)row0 * 4096 + kk * 1024 + (t & 63);

  // Prologue: issue row0's 4 dwordx4 loads (nontemporal: touch-once stream).
  f4 b0 = __builtin_nontemporal_load(in4 + 0 * 256);
  f4 b1 = __builtin_nontemporal_load(in4 + 1 * 256);
  f4 b2 = __builtin_nontemporal_load(in4 + 2 * 256);
  f4 b3 = __builtin_nontemporal_load(in4 + 3 * 256);

#pragma unroll
  for (int r = 0; r < ROWS; ++r) {
    if (row0 + r >= nrows) break;  // uniform within block

    // ---- Phase-1a: consume staging regs; radix-4 over bits {1:0}.
    // Thread t holds idx = kk*1024 + 4t + jj.
    float v[16];
    v[0] = b0.x; v[1] = b0.y; v[2] = b0.z; v[3] = b0.w;
    fwht4(v[0], v[1], v[2], v[3]);
    v[4] = b1.x; v[5] = b1.y; v[6] = b1.z; v[7] = b1.w;
    fwht4(v[4], v[5], v[6], v[7]);
    v[8] = b2.x; v[9] = b2.y; v[10] = b2.z; v[11] = b2.w;
    fwht4(v[8], v[9], v[10], v[11]);
    v[12] = b3.x; v[13] = b3.y; v[14] = b3.z; v[15] = b3.w;
    fwht4(v[12], v[13], v[14], v[15]);

    // ---- Prefetch next row NOW: staging regs are free, and the HBM read
    //      latency hides under this row's entire LDS/VALU/store tail.
    if (r + 1 < ROWS && row0 + r + 1 < nrows) {
      const f4* nx = in4 + (size_t)(r + 1) * 1024;
      b0 = __builtin_nontemporal_load(nx + 0 * 256);
      b1 = __builtin_nontemporal_load(nx + 1 * 256);
      b2 = __builtin_nontemporal_load(nx + 2 * 256);
      b3 = __builtin_nontemporal_load(nx + 3 * 256);
    }

    // ---- Phase-1b: radix-4 over bits {11:10} (the kk register dimension).
#pragma unroll
    for (int j = 0; j < 4; ++j) fwht4(v[0 + j], v[4 + j], v[8 + j], v[12 + j]);

    // WAR barrier: previous iteration's T2-read must finish before T1-write
    // (single LDS buffer; double-buffering would exceed 160 KB/CU at 8 blk/CU).
    __syncthreads();

    // ---- Transpose-1 write: contiguous 4-word groups -> ds_write_b128.
#pragma unroll
    for (int c = 0; c < 4; ++c) {
      f4 w = {v[c * 4 + 0], v[c * 4 + 1], v[c * 4 + 2], v[c * 4 + 3]};
      *reinterpret_cast<f4*>(&lds[pad(c * 1024 + 4 * t)]) = w;
    }
    __syncthreads();

    // ---- Transpose-1 read: thread (kk,ss,jj) gathers q=0..15 at
    //      idx = kk*1024 + ss*64 + 4q + jj; padded base + 16B offsets.
#pragma unroll
    for (int q = 0; q < 16; ++q) v[q] = lds[a1base + 4 * q];

    // ---- Phase 2: H16 over element bits {5:2}
    fwht16(v);

    // ---- Transpose-2 write: self-owned addresses (same as just read).
#pragma unroll
    for (int q = 0; q < 16; ++q) lds[a1base + 4 * q] = v[q];
    __syncthreads();

    // ---- Transpose-2 read: thread (kk,qq,jj) gathers s=0..15 at
    //      idx = kk*1024 + 64s + 4qq + jj; padded stride = 68 words.
#pragma unroll
    for (int s = 0; s < 16; ++s) v[s] = lds[a2base + 68 * s];

    // ---- Phase 3: H16 over element bits {9:6}, scaled by 1/sqrt(4096).
    fwht16(v);

    // ---- Store: per s, lanes cover 256 contiguous bytes (coalesced dwords).
    //      Nontemporal: write-once stream, don't allocate in L2/L3.
    float* o = op + (size_t)r * 4096;
#pragma unroll
    for (int s = 0; s < 16; ++s)
      __builtin_nontemporal_store(v[s] * 0.015625f, o + 64 * s);
  }
}

extern "C" void kernel_launch(void* const* d_in, const int* in_sizes, int n_in,
                              void* d_out, int out_size, void* d_ws, size_t ws_size,
                              hipStream_t stream) {
  const float* x = (const float*)d_in[0];
  float* out = (float*)d_out;
  const int rows = in_sizes[0] >> 12;  // 8192 rows of 4096
  const int blocks = (rows + ROWS - 1) / ROWS;
  hipLaunchKernelGGL(hadamard4096_kernel, dim3(blocks), dim3(THREADS), 0, stream,
                     x, out, rows);
}